// Round 1
// baseline (354.693 us; speedup 1.0000x reference)
//
#include <hip/hip_runtime.h>

typedef __attribute__((ext_vector_type(8))) __bf16 bf16x8;
typedef __attribute__((ext_vector_type(4))) float floatx4;

#define WS_BIAS  131072   // 16384 f32 : 16*sigmoid(cpb) per [h][n][m]
#define WS_SCALE 196608   // 4 f32     : exp(min(logit_scale, log 100))
#define WS_TBL   196640   // 900 f32   : cpb table (225 x 4)

static __device__ __forceinline__ unsigned short f2bf_u(float f) {
  union { __bf16 b; unsigned short u; } cv; cv.b = (__bf16)f; return cv.u;
}

// ---- prep: fp32 weights -> bf16 in ws; logit scale ----
__global__ void k_prep_weights(const float* __restrict__ qkv_w,
                               const float* __restrict__ proj_w,
                               const float* __restrict__ logit_scale,
                               unsigned short* __restrict__ wsQ,
                               float* __restrict__ wsScale)
{
  int t = blockIdx.x * 256 + threadIdx.x;   // 0..16383
  int i4 = t * 4;
  float4 v;
  if (i4 < 49152) v = *reinterpret_cast<const float4*>(qkv_w + i4);
  else            v = *reinterpret_cast<const float4*>(proj_w + (i4 - 49152));
  ushort4 pk;
  pk.x = f2bf_u(v.x); pk.y = f2bf_u(v.y); pk.z = f2bf_u(v.z); pk.w = f2bf_u(v.w);
  *reinterpret_cast<ushort4*>(wsQ + i4) = pk;
  if (t < 4) wsScale[t] = expf(fminf(logit_scale[t], 4.6051702f));
}

// ---- prep: CPB MLP table (225 x 4), one block per table row ----
__global__ void k_cpb_table(const float* __restrict__ w1, const float* __restrict__ b1,
                            const float* __restrict__ w2, float* __restrict__ tbl)
{
  __shared__ float red[256][4];
  int t = blockIdx.x;                  // 0..224
  int i = t / 15, j = t % 15;
  float c0 = 8.f * (float)(i - 7) / 7.f;
  float c1 = 8.f * (float)(j - 7) / 7.f;
  c0 = copysignf(log2f(fabsf(c0) + 1.f) / 3.f, c0);
  c1 = copysignf(log2f(fabsf(c1) + 1.f) / 3.f, c1);
  float a0 = 0.f, a1 = 0.f, a2 = 0.f, a3 = 0.f;
  for (int k = threadIdx.x; k < 512; k += 256) {
    float hd = fmaxf(c0 * w1[2*k] + c1 * w1[2*k+1] + b1[k], 0.f);
    a0 += hd * w2[k]; a1 += hd * w2[512+k]; a2 += hd * w2[1024+k]; a3 += hd * w2[1536+k];
  }
  red[threadIdx.x][0]=a0; red[threadIdx.x][1]=a1; red[threadIdx.x][2]=a2; red[threadIdx.x][3]=a3;
  __syncthreads();
  for (int s = 128; s > 0; s >>= 1) {
    if (threadIdx.x < (unsigned)s) {
      red[threadIdx.x][0] += red[threadIdx.x+s][0];
      red[threadIdx.x][1] += red[threadIdx.x+s][1];
      red[threadIdx.x][2] += red[threadIdx.x+s][2];
      red[threadIdx.x][3] += red[threadIdx.x+s][3];
    }
    __syncthreads();
  }
  if (threadIdx.x < 4) tbl[t*4 + threadIdx.x] = red[0][threadIdx.x];
}

// ---- prep: bias[h][n][m] = 16*sigmoid(tbl[rel(n,m)][h]) ----
__global__ void k_cpb_bias(const float* __restrict__ tbl, float* __restrict__ biasT)
{
  int idx = blockIdx.x * 256 + threadIdx.x;   // 0..16383
  int hh = idx >> 12, n = (idx >> 6) & 63, m = idx & 63;
  int rel = ((n >> 3) - (m >> 3) + 7) * 15 + ((n & 7) - (m & 7) + 7);
  float bv = tbl[rel * 4 + hh];
  biasT[idx] = 16.f / (1.f + expf(-bv));
}

// ---- main fused kernel: 1 block per window, wave h = head h ----
__global__ __launch_bounds__(256, 2) void k_wmsa(
    const float* __restrict__ x, const float* __restrict__ mask,
    const unsigned short* __restrict__ wqkv, const unsigned short* __restrict__ wproj,
    const float* __restrict__ q_bias, const float* __restrict__ v_bias,
    const float* __restrict__ biasT, const float* __restrict__ scale4,
    const float* __restrict__ proj_b, float* __restrict__ out)
{
  __shared__ char s_x[64 * 256];     // x bf16 (later O bf16), 256B rows, swizzled
  __shared__ char s_qk[4][8192];     // per head: q 4KB + k 4KB; later P 8KB
  __shared__ char s_vT[4][4096];     // per head: v^T 32x64 bf16

  const int b    = blockIdx.x;
  const int tid  = threadIdx.x;
  const int lane = tid & 63;
  const int h    = tid >> 6;
  const int l15  = lane & 15;
  const int lh   = lane >> 4;
  const floatx4 zf4 = {0.f, 0.f, 0.f, 0.f};

  // Phase 0: stage x tile (64x128 fp32) -> bf16 swizzled LDS
  {
    const float* xb = x + (size_t)b * 8192;
    int r = tid >> 2;
    #pragma unroll
    for (int cc = 0; cc < 8; ++cc) {
      int c = (tid & 3) + cc * 4;   // float4 chunk 0..31
      float4 v = reinterpret_cast<const float4*>(xb)[r * 32 + c];
      union { ushort4 s; uint2 u; } pk;
      pk.s.x = f2bf_u(v.x); pk.s.y = f2bf_u(v.y);
      pk.s.z = f2bf_u(v.z); pk.s.w = f2bf_u(v.w);
      *reinterpret_cast<uint2*>(s_x + r * 256 + ((c * 8) ^ ((r & 7) << 4))) = pk.u;
    }
  }
  __syncthreads();

  // Phase 1: qkv GEMM. wave h computes q,k,v (64x32 each), j: 0,1=q 2,3=k 4,5=v
  floatx4 acc[4][6];
  #pragma unroll
  for (int mt = 0; mt < 4; ++mt)
    #pragma unroll
    for (int j = 0; j < 6; ++j) acc[mt][j] = zf4;

  const int fb0 = h * 32;
  #pragma unroll
  for (int kk = 0; kk < 4; ++kk) {
    bf16x8 afrag[4];
    #pragma unroll
    for (int mt = 0; mt < 4; ++mt) {
      int row = mt * 16 + l15;
      afrag[mt] = *reinterpret_cast<const bf16x8*>(
          s_x + row * 256 + (((kk * 32 + lh * 8) * 2) ^ ((row & 7) << 4)));
    }
    #pragma unroll
    for (int j = 0; j < 6; ++j) {
      int f = (j >> 1) * 128 + fb0 + (j & 1) * 16 + l15;
      bf16x8 bfrag = *reinterpret_cast<const bf16x8*>(wqkv + f * 128 + kk * 32 + lh * 8);
      #pragma unroll
      for (int mt = 0; mt < 4; ++mt)
        acc[mt][j] = __builtin_amdgcn_mfma_f32_16x16x32_bf16(afrag[mt], bfrag, acc[mt][j], 0, 0, 0);
    }
  }

  // biases + cosine-normalize rows (fold logit scale into q)
  const float sc = scale4[h];
  {
    float qb0 = q_bias[fb0 + l15], qb1 = q_bias[fb0 + 16 + l15];
    float vb0 = v_bias[fb0 + l15], vb1 = v_bias[fb0 + 16 + l15];
    #pragma unroll
    for (int mt = 0; mt < 4; ++mt) {
      #pragma unroll
      for (int r = 0; r < 4; ++r) {
        acc[mt][0][r] += qb0; acc[mt][1][r] += qb1;
        acc[mt][4][r] += vb0; acc[mt][5][r] += vb1;
        float s = acc[mt][0][r]*acc[mt][0][r] + acc[mt][1][r]*acc[mt][1][r];
        s += __shfl_xor(s, 1); s += __shfl_xor(s, 2);
        s += __shfl_xor(s, 4); s += __shfl_xor(s, 8);
        float rq = sc / fmaxf(sqrtf(s), 1e-12f);
        acc[mt][0][r] *= rq; acc[mt][1][r] *= rq;
        float s2 = acc[mt][2][r]*acc[mt][2][r] + acc[mt][3][r]*acc[mt][3][r];
        s2 += __shfl_xor(s2, 1); s2 += __shfl_xor(s2, 2);
        s2 += __shfl_xor(s2, 4); s2 += __shfl_xor(s2, 8);
        float rk = 1.f / fmaxf(sqrtf(s2), 1e-12f);
        acc[mt][2][r] *= rk; acc[mt][3][r] *= rk;
      }
    }
  }

  // write qn,kn (64x32, 64B rows, swz (row&3)<<4) and v^T (32x64, 128B rows, swz (d&7)<<4)
  {
    char* sq = s_qk[h];
    char* sv = s_vT[h];
    #pragma unroll
    for (int mt = 0; mt < 4; ++mt) {
      #pragma unroll
      for (int r = 0; r < 4; ++r) {
        int row = mt * 16 + lh * 4 + r;
        #pragma unroll
        for (int j = 0; j < 2; ++j) {
          int col2 = (j * 16 + l15) * 2;
          int swq = col2 ^ ((row & 3) << 4);
          *reinterpret_cast<__bf16*>(sq + row * 64 + swq)        = (__bf16)acc[mt][j][r];
          *reinterpret_cast<__bf16*>(sq + 4096 + row * 64 + swq) = (__bf16)acc[mt][2 + j][r];
          int d = j * 16 + l15;
          *reinterpret_cast<__bf16*>(sv + d * 128 + ((row * 2) ^ ((d & 7) << 4)))
              = (__bf16)acc[mt][4 + j][r];
        }
      }
    }
  }
  __syncthreads();

  // Phase 2: S = qn @ kn^T  (64x64, K=32 -> single MFMA step)
  floatx4 sacc[4][4];
  {
    const char* sq = s_qk[h];
    bf16x8 aq[4], bk[4];
    #pragma unroll
    for (int mt = 0; mt < 4; ++mt) {
      int row = mt * 16 + l15;
      aq[mt] = *reinterpret_cast<const bf16x8*>(sq + row * 64 + ((lh * 16) ^ ((row & 3) << 4)));
    }
    #pragma unroll
    for (int nt = 0; nt < 4; ++nt) {
      int m = nt * 16 + l15;
      bk[nt] = *reinterpret_cast<const bf16x8*>(sq + 4096 + m * 64 + ((lh * 16) ^ ((m & 3) << 4)));
    }
    #pragma unroll
    for (int mt = 0; mt < 4; ++mt)
      #pragma unroll
      for (int nt = 0; nt < 4; ++nt)
        sacc[mt][nt] = __builtin_amdgcn_mfma_f32_16x16x32_bf16(aq[mt], bk[nt], zf4, 0, 0, 0);
  }

  // Phase 3: +bias +mask, softmax over m, write P bf16 (64x64, 128B rows, swz (n&7)<<4)
  {
    const float* bh = biasT + h * 4096;
    const float* mw = mask + (size_t)(b & 255) * 4096;
    char* sp = s_qk[h];
    #pragma unroll
    for (int mt = 0; mt < 4; ++mt) {
      #pragma unroll
      for (int r = 0; r < 4; ++r) {
        int n = mt * 16 + lh * 4 + r;
        float v0 = sacc[mt][0][r] + bh[n*64 + l15]      + mw[n*64 + l15];
        float v1 = sacc[mt][1][r] + bh[n*64 + 16 + l15] + mw[n*64 + 16 + l15];
        float v2 = sacc[mt][2][r] + bh[n*64 + 32 + l15] + mw[n*64 + 32 + l15];
        float v3 = sacc[mt][3][r] + bh[n*64 + 48 + l15] + mw[n*64 + 48 + l15];
        float mx = fmaxf(fmaxf(v0, v1), fmaxf(v2, v3));
        mx = fmaxf(mx, __shfl_xor(mx, 1)); mx = fmaxf(mx, __shfl_xor(mx, 2));
        mx = fmaxf(mx, __shfl_xor(mx, 4)); mx = fmaxf(mx, __shfl_xor(mx, 8));
        v0 = __expf(v0 - mx); v1 = __expf(v1 - mx);
        v2 = __expf(v2 - mx); v3 = __expf(v3 - mx);
        float sm = v0 + v1 + v2 + v3;
        sm += __shfl_xor(sm, 1); sm += __shfl_xor(sm, 2);
        sm += __shfl_xor(sm, 4); sm += __shfl_xor(sm, 8);
        float rs = 1.f / sm;
        int base = n * 128, sw = (n & 7) << 4;
        *reinterpret_cast<__bf16*>(sp + base + (((l15     ) * 2) ^ sw)) = (__bf16)(v0 * rs);
        *reinterpret_cast<__bf16*>(sp + base + (((16 + l15) * 2) ^ sw)) = (__bf16)(v1 * rs);
        *reinterpret_cast<__bf16*>(sp + base + (((32 + l15) * 2) ^ sw)) = (__bf16)(v2 * rs);
        *reinterpret_cast<__bf16*>(sp + base + (((48 + l15) * 2) ^ sw)) = (__bf16)(v3 * rs);
      }
    }
  }
  __syncthreads();

  // Phase 4: O = P @ V  (64x32, K=64)
  floatx4 oacc[4][2];
  #pragma unroll
  for (int mt = 0; mt < 4; ++mt) { oacc[mt][0] = zf4; oacc[mt][1] = zf4; }
  {
    const char* sp = s_qk[h];
    const char* sv = s_vT[h];
    #pragma unroll
    for (int kk = 0; kk < 2; ++kk) {
      bf16x8 ap[4];
      #pragma unroll
      for (int mt = 0; mt < 4; ++mt) {
        int row = mt * 16 + l15;
        ap[mt] = *reinterpret_cast<const bf16x8*>(
            sp + row * 128 + (((kk * 32 + lh * 8) * 2) ^ ((row & 7) << 4)));
      }
      #pragma unroll
      for (int nd = 0; nd < 2; ++nd) {
        int d = nd * 16 + l15;
        bf16x8 bv = *reinterpret_cast<const bf16x8*>(
            sv + d * 128 + (((kk * 32 + lh * 8) * 2) ^ ((d & 7) << 4)));
        #pragma unroll
        for (int mt = 0; mt < 4; ++mt)
          oacc[mt][nd] = __builtin_amdgcn_mfma_f32_16x16x32_bf16(ap[mt], bv, oacc[mt][nd], 0, 0, 0);
      }
    }
  }
  // write O (bf16) into s_x cols [h*32, h*32+32)
  #pragma unroll
  for (int mt = 0; mt < 4; ++mt) {
    #pragma unroll
    for (int r = 0; r < 4; ++r) {
      int n = mt * 16 + lh * 4 + r;
      #pragma unroll
      for (int nd = 0; nd < 2; ++nd) {
        int c = h * 32 + nd * 16 + l15;
        *reinterpret_cast<__bf16*>(s_x + n * 256 + ((c * 2) ^ ((n & 7) << 4)))
            = (__bf16)oacc[mt][nd][r];
      }
    }
  }
  __syncthreads();

  // Phase 5: proj GEMM + bias, store fp32
  floatx4 pacc[4][2];
  #pragma unroll
  for (int mt = 0; mt < 4; ++mt) { pacc[mt][0] = zf4; pacc[mt][1] = zf4; }
  #pragma unroll
  for (int kk = 0; kk < 4; ++kk) {
    bf16x8 af[4];
    #pragma unroll
    for (int mt = 0; mt < 4; ++mt) {
      int row = mt * 16 + l15;
      af[mt] = *reinterpret_cast<const bf16x8*>(
          s_x + row * 256 + (((kk * 32 + lh * 8) * 2) ^ ((row & 7) << 4)));
    }
    #pragma unroll
    for (int nt = 0; nt < 2; ++nt) {
      int f = h * 32 + nt * 16 + l15;
      bf16x8 bw = *reinterpret_cast<const bf16x8*>(wproj + f * 128 + kk * 32 + lh * 8);
      #pragma unroll
      for (int mt = 0; mt < 4; ++mt)
        pacc[mt][nt] = __builtin_amdgcn_mfma_f32_16x16x32_bf16(af[mt], bw, pacc[mt][nt], 0, 0, 0);
    }
  }
  {
    float pb0 = proj_b[h*32 + l15], pb1 = proj_b[h*32 + 16 + l15];
    float* ob = out + (size_t)b * 8192;
    #pragma unroll
    for (int mt = 0; mt < 4; ++mt)
      #pragma unroll
      for (int r = 0; r < 4; ++r) {
        int n = mt * 16 + lh * 4 + r;
        ob[n * 128 + h*32 + l15]      = pacc[mt][0][r] + pb0;
        ob[n * 128 + h*32 + 16 + l15] = pacc[mt][1][r] + pb1;
      }
  }
}

extern "C" void kernel_launch(void* const* d_in, const int* in_sizes, int n_in,
                              void* d_out, int out_size, void* d_ws, size_t ws_size,
                              hipStream_t stream)
{
  const float* x    = (const float*)d_in[0];
  const float* mask = (const float*)d_in[1];
  const float* qkvw = (const float*)d_in[2];
  const float* qb   = (const float*)d_in[3];
  const float* vb   = (const float*)d_in[4];
  const float* ls   = (const float*)d_in[5];
  const float* w1   = (const float*)d_in[6];
  const float* b1   = (const float*)d_in[7];
  const float* w2   = (const float*)d_in[8];
  const float* pw   = (const float*)d_in[9];
  const float* pb   = (const float*)d_in[10];
  float* out = (float*)d_out;
  char* ws = (char*)d_ws;

  unsigned short* wsQ = (unsigned short*)ws;          // qkv bf16 [0,49152) + proj bf16 [49152,65536)
  float* wsBias  = (float*)(ws + WS_BIAS);
  float* wsScale = (float*)(ws + WS_SCALE);
  float* wsTbl   = (float*)(ws + WS_TBL);

  hipLaunchKernelGGL(k_prep_weights, dim3(64), dim3(256), 0, stream, qkvw, pw, ls, wsQ, wsScale);
  hipLaunchKernelGGL(k_cpb_table, dim3(225), dim3(256), 0, stream, w1, b1, w2, wsTbl);
  hipLaunchKernelGGL(k_cpb_bias, dim3(64), dim3(256), 0, stream, wsTbl, wsBias);
  hipLaunchKernelGGL(k_wmsa, dim3(8192), dim3(256), 0, stream, x, mask,
                     wsQ, wsQ + 49152, qb, vb, wsBias, wsScale, pb, out);
}

// Round 2
// 337.984 us; speedup vs baseline: 1.0494x; 1.0494x over previous
//
#include <hip/hip_runtime.h>

typedef __attribute__((ext_vector_type(8))) __bf16 bf16x8;
typedef __attribute__((ext_vector_type(4))) float floatx4;

#define WS_BIAS  131072   // 16384 f32 : 16*sigmoid(cpb) per [h][n][m]
#define WS_SCALE 196608   // 4 f32     : exp(min(logit_scale, log 100))
#define WS_TBL   196640   // 900 f32   : cpb table (225 x 4)

static __device__ __forceinline__ unsigned short f2bf_u(float f) {
  union { __bf16 b; unsigned short u; } cv; cv.b = (__bf16)f; return cv.u;
}
static __device__ __forceinline__ unsigned pkbf(float lo, float hi) {
  union { __bf16 b[2]; unsigned u; } cv; cv.b[0] = (__bf16)lo; cv.b[1] = (__bf16)hi; return cv.u;
}

// In-register transpose regroup: input val0/val1 are MFMA C-layout accs holding
// M[16t+4*lh+r][l15] (t=0: val0, t=1: val1). Output bf16x8 A/B-frag where lane
// (l15,lh) holds elements M[8*lh+j][l15], j=0..7.
static __device__ __forceinline__ bf16x8 regroup2(floatx4 v0, floatx4 v1,
                                                  int s0, int s1, bool hi) {
  unsigned p00 = pkbf(v0[0], v0[1]);
  unsigned p01 = pkbf(v0[2], v0[3]);
  unsigned p10 = pkbf(v1[0], v1[1]);
  unsigned p11 = pkbf(v1[2], v1[3]);
  unsigned a0 = __shfl(p00, s0), b0 = __shfl(p10, s0);
  unsigned a1 = __shfl(p01, s0), b1 = __shfl(p11, s0);
  unsigned a2 = __shfl(p00, s1), b2 = __shfl(p10, s1);
  unsigned a3 = __shfl(p01, s1), b3 = __shfl(p11, s1);
  union { unsigned u[4]; bf16x8 v; } fr;
  fr.u[0] = hi ? b0 : a0;
  fr.u[1] = hi ? b1 : a1;
  fr.u[2] = hi ? b2 : a2;
  fr.u[3] = hi ? b3 : a3;
  return fr.v;
}

// ---- prep: fp32 weights -> bf16 in ws; logit scale ----
__global__ void k_prep_weights(const float* __restrict__ qkv_w,
                               const float* __restrict__ proj_w,
                               const float* __restrict__ logit_scale,
                               unsigned short* __restrict__ wsQ,
                               float* __restrict__ wsScale)
{
  int t = blockIdx.x * 256 + threadIdx.x;   // 0..16383
  int i4 = t * 4;
  float4 v;
  if (i4 < 49152) v = *reinterpret_cast<const float4*>(qkv_w + i4);
  else            v = *reinterpret_cast<const float4*>(proj_w + (i4 - 49152));
  ushort4 pk;
  pk.x = f2bf_u(v.x); pk.y = f2bf_u(v.y); pk.z = f2bf_u(v.z); pk.w = f2bf_u(v.w);
  *reinterpret_cast<ushort4*>(wsQ + i4) = pk;
  if (t < 4) wsScale[t] = expf(fminf(logit_scale[t], 4.6051702f));
}

// ---- prep: CPB MLP table (225 x 4), one block per table row ----
__global__ void k_cpb_table(const float* __restrict__ w1, const float* __restrict__ b1,
                            const float* __restrict__ w2, float* __restrict__ tbl)
{
  __shared__ float red[256][4];
  int t = blockIdx.x;                  // 0..224
  int i = t / 15, j = t % 15;
  float c0 = 8.f * (float)(i - 7) / 7.f;
  float c1 = 8.f * (float)(j - 7) / 7.f;
  c0 = copysignf(log2f(fabsf(c0) + 1.f) / 3.f, c0);
  c1 = copysignf(log2f(fabsf(c1) + 1.f) / 3.f, c1);
  float a0 = 0.f, a1 = 0.f, a2 = 0.f, a3 = 0.f;
  for (int k = threadIdx.x; k < 512; k += 256) {
    float hd = fmaxf(c0 * w1[2*k] + c1 * w1[2*k+1] + b1[k], 0.f);
    a0 += hd * w2[k]; a1 += hd * w2[512+k]; a2 += hd * w2[1024+k]; a3 += hd * w2[1536+k];
  }
  red[threadIdx.x][0]=a0; red[threadIdx.x][1]=a1; red[threadIdx.x][2]=a2; red[threadIdx.x][3]=a3;
  __syncthreads();
  for (int s = 128; s > 0; s >>= 1) {
    if (threadIdx.x < (unsigned)s) {
      red[threadIdx.x][0] += red[threadIdx.x+s][0];
      red[threadIdx.x][1] += red[threadIdx.x+s][1];
      red[threadIdx.x][2] += red[threadIdx.x+s][2];
      red[threadIdx.x][3] += red[threadIdx.x+s][3];
    }
    __syncthreads();
  }
  if (threadIdx.x < 4) tbl[t*4 + threadIdx.x] = red[0][threadIdx.x];
}

// ---- prep: bias[h][n][m] = 16*sigmoid(tbl[rel(n,m)][h]) ----
__global__ void k_cpb_bias(const float* __restrict__ tbl, float* __restrict__ biasT)
{
  int idx = blockIdx.x * 256 + threadIdx.x;   // 0..16383
  int hh = idx >> 12, n = (idx >> 6) & 63, m = idx & 63;
  int rel = ((n >> 3) - (m >> 3) + 7) * 15 + ((n & 7) - (m & 7) + 7);
  float bv = tbl[rel * 4 + hh];
  biasT[idx] = 16.f / (1.f + expf(-bv));
}

// ---- main fused kernel: 1 block per window, wave h = head h ----
__global__ __launch_bounds__(256, 4) void k_wmsa(
    const float* __restrict__ x, const float* __restrict__ mask,
    const unsigned short* __restrict__ wqkv, const unsigned short* __restrict__ wproj,
    const float* __restrict__ q_bias, const float* __restrict__ v_bias,
    const float* __restrict__ biasT, const float* __restrict__ scale4,
    const float* __restrict__ proj_b, float* __restrict__ out)
{
  __shared__ char s_x[64 * 256];     // x bf16 swizzled; later O [n][c] bf16
  __shared__ char s_vT[4][4096];     // per head vT [32][64] bf16, 128B rows, swz (d&7)<<4

  const int b    = blockIdx.x;
  const int tid  = threadIdx.x;
  const int lane = tid & 63;
  const int h    = tid >> 6;
  const int l15  = lane & 15;
  const int lh   = lane >> 4;
  const int s0   = l15 + ((lane & 16) << 1);   // l15 + 32*(lh&1)
  const int s1   = s0 + 16;
  const bool hi  = (lane & 32) != 0;           // lh>>1
  const floatx4 zf4 = {0.f, 0.f, 0.f, 0.f};

  // ---- Phase 0: stage x tile (64x128 fp32) -> bf16 swizzled LDS ----
  {
    const float* xb = x + (size_t)b * 8192;
    int r = tid >> 2;
    #pragma unroll
    for (int cc = 0; cc < 8; ++cc) {
      int c = (tid & 3) + cc * 4;
      float4 v = reinterpret_cast<const float4*>(xb)[r * 32 + c];
      uint2 w; w.x = pkbf(v.x, v.y); w.y = pkbf(v.z, v.w);
      *reinterpret_cast<uint2*>(s_x + r * 256 + ((c * 8) ^ ((r & 7) << 4))) = w;
    }
  }
  __syncthreads();

  // ---- Phase 1a: v = x @ Wv^T  (normal orientation; acc lane col = feature) ----
  floatx4 vacc[4][2];
  #pragma unroll
  for (int mt = 0; mt < 4; ++mt) { vacc[mt][0] = zf4; vacc[mt][1] = zf4; }
  #pragma unroll
  for (int kk = 0; kk < 4; ++kk) {
    bf16x8 xf[4];
    #pragma unroll
    for (int tt = 0; tt < 4; ++tt) {
      int row = tt * 16 + l15;
      xf[tt] = *reinterpret_cast<const bf16x8*>(
          s_x + row * 256 + (((kk * 32 + lh * 8) * 2) ^ ((row & 7) << 4)));
    }
    #pragma unroll
    for (int ft = 0; ft < 2; ++ft) {
      bf16x8 wv = *reinterpret_cast<const bf16x8*>(
          wqkv + (size_t)(256 + h * 32 + ft * 16 + l15) * 128 + kk * 32 + lh * 8);
      #pragma unroll
      for (int mt = 0; mt < 4; ++mt)
        vacc[mt][ft] = __builtin_amdgcn_mfma_f32_16x16x32_bf16(xf[mt], wv, vacc[mt][ft], 0, 0, 0);
    }
  }
  // v bias; write vT[d][m] with b64-packed writes (lane owns 4 consecutive m)
  {
    float vb0 = v_bias[h * 32 + l15], vb1 = v_bias[h * 32 + 16 + l15];
    char* sv = s_vT[h];
    #pragma unroll
    for (int mt = 0; mt < 4; ++mt) {
      #pragma unroll
      for (int ft = 0; ft < 2; ++ft) {
        float vb = ft ? vb1 : vb0;
        int d = ft * 16 + l15;
        uint2 w;
        w.x = pkbf(vacc[mt][ft][0] + vb, vacc[mt][ft][1] + vb);
        w.y = pkbf(vacc[mt][ft][2] + vb, vacc[mt][ft][3] + vb);
        *reinterpret_cast<uint2*>(sv + d * 128 + (((mt * 16 + lh * 4) * 2) ^ ((d & 7) << 4))) = w;
      }
    }
  }

  // ---- Phase 1b: q^T,k^T = W_qk @ x^T (transposed; acc lane col = TOKEN) ----
  floatx4 qk[4][4];   // [ff: q0,q1,k0,k1][token tile]
  #pragma unroll
  for (int ff = 0; ff < 4; ++ff)
    #pragma unroll
    for (int tt = 0; tt < 4; ++tt) qk[ff][tt] = zf4;
  #pragma unroll
  for (int kk = 0; kk < 4; ++kk) {
    bf16x8 xf[4];
    #pragma unroll
    for (int tt = 0; tt < 4; ++tt) {
      int row = tt * 16 + l15;
      xf[tt] = *reinterpret_cast<const bf16x8*>(
          s_x + row * 256 + (((kk * 32 + lh * 8) * 2) ^ ((row & 7) << 4)));
    }
    #pragma unroll
    for (int ff = 0; ff < 4; ++ff) {
      int fb = (ff < 2) ? (h * 32 + ff * 16) : (128 + h * 32 + (ff - 2) * 16);
      bf16x8 wf = *reinterpret_cast<const bf16x8*>(
          wqkv + (size_t)(fb + l15) * 128 + kk * 32 + lh * 8);
      #pragma unroll
      for (int tt = 0; tt < 4; ++tt)
        qk[ff][tt] = __builtin_amdgcn_mfma_f32_16x16x32_bf16(wf, xf[tt], qk[ff][tt], 0, 0, 0);
    }
  }
  // q bias (vectorized over the 4 row-regs), then lane-local norms
  {
    floatx4 qb0 = *reinterpret_cast<const floatx4*>(q_bias + h * 32 + lh * 4);
    floatx4 qb1 = *reinterpret_cast<const floatx4*>(q_bias + h * 32 + 16 + lh * 4);
    #pragma unroll
    for (int tt = 0; tt < 4; ++tt)
      #pragma unroll
      for (int r = 0; r < 4; ++r) { qk[0][tt][r] += qb0[r]; qk[1][tt][r] += qb1[r]; }
  }
  const float sc = scale4[h];
  #pragma unroll
  for (int tt = 0; tt < 4; ++tt) {
    float sq = 0.f, sk = 0.f;
    #pragma unroll
    for (int r = 0; r < 4; ++r) {
      sq += qk[0][tt][r] * qk[0][tt][r] + qk[1][tt][r] * qk[1][tt][r];
      sk += qk[2][tt][r] * qk[2][tt][r] + qk[3][tt][r] * qk[3][tt][r];
    }
    sq += __shfl_xor(sq, 16); sq += __shfl_xor(sq, 32);
    sk += __shfl_xor(sk, 16); sk += __shfl_xor(sk, 32);
    float rq = sc  / fmaxf(sqrtf(sq), 1e-12f);
    float rk = 1.f / fmaxf(sqrtf(sk), 1e-12f);
    #pragma unroll
    for (int r = 0; r < 4; ++r) {
      qk[0][tt][r] *= rq; qk[1][tt][r] *= rq;
      qk[2][tt][r] *= rk; qk[3][tt][r] *= rk;
    }
  }

  // ---- Phase 2: S^T = kn @ qn^T  (in-register operand regroup, no LDS) ----
  floatx4 sacc[4][4];   // [m tile][n tile]; lane: rows m=16tm+4lh+r, col n=16tn+l15
  {
    bf16x8 qf[4], kf[4];
    #pragma unroll
    for (int tt = 0; tt < 4; ++tt) {
      qf[tt] = regroup2(qk[0][tt], qk[1][tt], s0, s1, hi);
      kf[tt] = regroup2(qk[2][tt], qk[3][tt], s0, s1, hi);
    }
    #pragma unroll
    for (int tm = 0; tm < 4; ++tm)
      #pragma unroll
      for (int tn = 0; tn < 4; ++tn)
        sacc[tm][tn] = __builtin_amdgcn_mfma_f32_16x16x32_bf16(kf[tm], qf[tn], zf4, 0, 0, 0);
  }

  // ---- Phase 3: +bias +mask, exp (no max-sub: logits bounded), col sums ----
  floatx4 rs;
  {
    const float* bh = biasT + h * 4096;
    const float* mw = mask + (size_t)(b & 255) * 4096;
    floatx4 sm = zf4;
    #pragma unroll
    for (int tm = 0; tm < 4; ++tm) {
      #pragma unroll
      for (int tn = 0; tn < 4; ++tn) {
        int off = (tn * 16 + l15) * 64 + tm * 16 + lh * 4;
        floatx4 bb = *reinterpret_cast<const floatx4*>(bh + off);
        floatx4 mm = *reinterpret_cast<const floatx4*>(mw + off);
        #pragma unroll
        for (int r = 0; r < 4; ++r) {
          float e = __expf(sacc[tm][tn][r] + bb[r] + mm[r]);
          sacc[tm][tn][r] = e;
          sm[tn] += e;
        }
      }
    }
    #pragma unroll
    for (int tn = 0; tn < 4; ++tn) {
      float s = sm[tn];
      s += __shfl_xor(s, 16); s += __shfl_xor(s, 32);
      rs[tn] = 1.f / s;
    }
  }

  // ---- Phase 4: O^T = V^T @ P^T (P regrouped in-register; V^T from LDS) ----
  floatx4 oacc[2][4];
  #pragma unroll
  for (int dt = 0; dt < 2; ++dt)
    #pragma unroll
    for (int nt = 0; nt < 4; ++nt) oacc[dt][nt] = zf4;
  {
    const char* sv = s_vT[h];
    #pragma unroll
    for (int kk = 0; kk < 2; ++kk) {
      bf16x8 vf[2];
      #pragma unroll
      for (int dt = 0; dt < 2; ++dt)
        vf[dt] = *reinterpret_cast<const bf16x8*>(
            sv + (dt * 16 + l15) * 128 + (((kk * 32 + lh * 8) * 2) ^ ((l15 & 7) << 4)));
      #pragma unroll
      for (int nt = 0; nt < 4; ++nt) {
        bf16x8 pf = regroup2(sacc[kk * 2][nt], sacc[kk * 2 + 1][nt], s0, s1, hi);
        #pragma unroll
        for (int dt = 0; dt < 2; ++dt)
          oacc[dt][nt] = __builtin_amdgcn_mfma_f32_16x16x32_bf16(vf[dt], pf, oacc[dt][nt], 0, 0, 0);
      }
    }
  }
  __syncthreads();   // all waves done reading s_x (phase 1) before O overwrites it

  // O (scaled by 1/rowsum) -> s_x as [n][c] bf16, b64-packed writes
  #pragma unroll
  for (int dt = 0; dt < 2; ++dt) {
    #pragma unroll
    for (int nt = 0; nt < 4; ++nt) {
      int n = nt * 16 + l15;
      uint2 w;
      w.x = pkbf(oacc[dt][nt][0] * rs[nt], oacc[dt][nt][1] * rs[nt]);
      w.y = pkbf(oacc[dt][nt][2] * rs[nt], oacc[dt][nt][3] * rs[nt]);
      *reinterpret_cast<uint2*>(
          s_x + n * 256 + (((h * 32 + dt * 16 + lh * 4) * 2) ^ ((n & 7) << 4))) = w;
    }
  }
  __syncthreads();

  // ---- Phase 5: proj GEMM + bias, fp32 store ----
  floatx4 pacc[4][2];
  #pragma unroll
  for (int mt = 0; mt < 4; ++mt) { pacc[mt][0] = zf4; pacc[mt][1] = zf4; }
  #pragma unroll
  for (int kk = 0; kk < 4; ++kk) {
    bf16x8 of[4];
    #pragma unroll
    for (int mt = 0; mt < 4; ++mt) {
      int row = mt * 16 + l15;
      of[mt] = *reinterpret_cast<const bf16x8*>(
          s_x + row * 256 + (((kk * 32 + lh * 8) * 2) ^ ((row & 7) << 4)));
    }
    #pragma unroll
    for (int ft = 0; ft < 2; ++ft) {
      bf16x8 wp = *reinterpret_cast<const bf16x8*>(
          wproj + (size_t)(h * 32 + ft * 16 + l15) * 128 + kk * 32 + lh * 8);
      #pragma unroll
      for (int mt = 0; mt < 4; ++mt)
        pacc[mt][ft] = __builtin_amdgcn_mfma_f32_16x16x32_bf16(of[mt], wp, pacc[mt][ft], 0, 0, 0);
    }
  }
  {
    float pb0 = proj_b[h * 32 + l15], pb1 = proj_b[h * 32 + 16 + l15];
    float* ob = out + (size_t)b * 8192;
    #pragma unroll
    for (int mt = 0; mt < 4; ++mt)
      #pragma unroll
      for (int r = 0; r < 4; ++r) {
        int n = mt * 16 + lh * 4 + r;
        ob[n * 128 + h * 32 + l15]      = pacc[mt][0][r] + pb0;
        ob[n * 128 + h * 32 + 16 + l15] = pacc[mt][1][r] + pb1;
      }
  }
}

extern "C" void kernel_launch(void* const* d_in, const int* in_sizes, int n_in,
                              void* d_out, int out_size, void* d_ws, size_t ws_size,
                              hipStream_t stream)
{
  const float* x    = (const float*)d_in[0];
  const float* mask = (const float*)d_in[1];
  const float* qkvw = (const float*)d_in[2];
  const float* qb   = (const float*)d_in[3];
  const float* vb   = (const float*)d_in[4];
  const float* ls   = (const float*)d_in[5];
  const float* w1   = (const float*)d_in[6];
  const float* b1   = (const float*)d_in[7];
  const float* w2   = (const float*)d_in[8];
  const float* pw   = (const float*)d_in[9];
  const float* pb   = (const float*)d_in[10];
  float* out = (float*)d_out;
  char* ws = (char*)d_ws;

  unsigned short* wsQ = (unsigned short*)ws;   // qkv bf16 [0,49152) + proj bf16 [49152,65536)
  float* wsBias  = (float*)(ws + WS_BIAS);
  float* wsScale = (float*)(ws + WS_SCALE);
  float* wsTbl   = (float*)(ws + WS_TBL);

  hipLaunchKernelGGL(k_prep_weights, dim3(64), dim3(256), 0, stream, qkvw, pw, ls, wsQ, wsScale);
  hipLaunchKernelGGL(k_cpb_table, dim3(225), dim3(256), 0, stream, w1, b1, w2, wsTbl);
  hipLaunchKernelGGL(k_cpb_bias, dim3(64), dim3(256), 0, stream, wsTbl, wsBias);
  hipLaunchKernelGGL(k_wmsa, dim3(8192), dim3(256), 0, stream, x, mask,
                     wsQ, wsQ + 49152, qb, vb, wsBias, wsScale, pb, out);
}

// Round 3
// 314.354 us; speedup vs baseline: 1.1283x; 1.0752x over previous
//
#include <hip/hip_runtime.h>

typedef __attribute__((ext_vector_type(8))) __bf16 bf16x8;
typedef __attribute__((ext_vector_type(4))) float floatx4;

#define WS_BIAS  131072   // 16384 f32 : 16*sigmoid(cpb) per [h][n][m]
#define WS_SCALE 196608   // 4 f32     : exp(min(logit_scale, log 100))
#define WS_TBL   196640   // 900 f32   : cpb table (225 x 4)

static __device__ __forceinline__ unsigned short f2bf_u(float f) {
  union { __bf16 b; unsigned short u; } cv; cv.b = (__bf16)f; return cv.u;
}
static __device__ __forceinline__ unsigned pkbf(float lo, float hi) {
  union { __bf16 b[2]; unsigned u; } cv; cv.b[0] = (__bf16)lo; cv.b[1] = (__bf16)hi; return cv.u;
}

// ---- prep: fp32 weights -> bf16 in ws; logit scale ----
__global__ void k_prep_weights(const float* __restrict__ qkv_w,
                               const float* __restrict__ proj_w,
                               const float* __restrict__ logit_scale,
                               unsigned short* __restrict__ wsQ,
                               float* __restrict__ wsScale)
{
  int t = blockIdx.x * 256 + threadIdx.x;   // 0..16383
  int i4 = t * 4;
  float4 v;
  if (i4 < 49152) v = *reinterpret_cast<const float4*>(qkv_w + i4);
  else            v = *reinterpret_cast<const float4*>(proj_w + (i4 - 49152));
  ushort4 pk;
  pk.x = f2bf_u(v.x); pk.y = f2bf_u(v.y); pk.z = f2bf_u(v.z); pk.w = f2bf_u(v.w);
  *reinterpret_cast<ushort4*>(wsQ + i4) = pk;
  if (t < 4) wsScale[t] = expf(fminf(logit_scale[t], 4.6051702f));
}

// ---- prep: CPB MLP table (225 x 4), one block per table row ----
__global__ void k_cpb_table(const float* __restrict__ w1, const float* __restrict__ b1,
                            const float* __restrict__ w2, float* __restrict__ tbl)
{
  __shared__ float red[256][4];
  int t = blockIdx.x;                  // 0..224
  int i = t / 15, j = t % 15;
  float c0 = 8.f * (float)(i - 7) / 7.f;
  float c1 = 8.f * (float)(j - 7) / 7.f;
  c0 = copysignf(log2f(fabsf(c0) + 1.f) / 3.f, c0);
  c1 = copysignf(log2f(fabsf(c1) + 1.f) / 3.f, c1);
  float a0 = 0.f, a1 = 0.f, a2 = 0.f, a3 = 0.f;
  for (int k = threadIdx.x; k < 512; k += 256) {
    float hd = fmaxf(c0 * w1[2*k] + c1 * w1[2*k+1] + b1[k], 0.f);
    a0 += hd * w2[k]; a1 += hd * w2[512+k]; a2 += hd * w2[1024+k]; a3 += hd * w2[1536+k];
  }
  red[threadIdx.x][0]=a0; red[threadIdx.x][1]=a1; red[threadIdx.x][2]=a2; red[threadIdx.x][3]=a3;
  __syncthreads();
  for (int s = 128; s > 0; s >>= 1) {
    if (threadIdx.x < (unsigned)s) {
      red[threadIdx.x][0] += red[threadIdx.x+s][0];
      red[threadIdx.x][1] += red[threadIdx.x+s][1];
      red[threadIdx.x][2] += red[threadIdx.x+s][2];
      red[threadIdx.x][3] += red[threadIdx.x+s][3];
    }
    __syncthreads();
  }
  if (threadIdx.x < 4) tbl[t*4 + threadIdx.x] = red[0][threadIdx.x];
}

// ---- prep: bias[h][n][m] = 16*sigmoid(tbl[rel(n,m)][h]) ----
__global__ void k_cpb_bias(const float* __restrict__ tbl, float* __restrict__ biasT)
{
  int idx = blockIdx.x * 256 + threadIdx.x;   // 0..16383
  int hh = idx >> 12, n = (idx >> 6) & 63, m = idx & 63;
  int rel = ((n >> 3) - (m >> 3) + 7) * 15 + ((n & 7) - (m & 7) + 7);
  float bv = tbl[rel * 4 + hh];
  biasT[idx] = 16.f / (1.f + expf(-bv));
}

// ---- main fused kernel: 1 block per window, wave h = head h ----
__global__ __launch_bounds__(256, 2) void k_wmsa(
    const float* __restrict__ x, const float* __restrict__ mask,
    const unsigned short* __restrict__ wqkv, const unsigned short* __restrict__ wproj,
    const float* __restrict__ q_bias, const float* __restrict__ v_bias,
    const float* __restrict__ biasT, const float* __restrict__ scale4,
    const float* __restrict__ proj_b, float* __restrict__ out)
{
  __shared__ char s_x[64 * 256];     // 16KB: x bf16 swizzled; later O [n][c] bf16
  __shared__ char s_qk[4][8192];     // 32KB: per head q[64][32]+k[64][32]; later P[64][64]
  __shared__ char s_vT[4][4096];     // 16KB: per head vT[32][64] bf16, swz (d&7)<<4

  const int b    = blockIdx.x;
  const int tid  = threadIdx.x;
  const int lane = tid & 63;
  const int h    = tid >> 6;
  const int l15  = lane & 15;
  const int lh   = lane >> 4;
  const int swq  = ((l15 ^ (l15 >> 2)) & 3) << 4;  // q/k row swizzle (row = 16t+l15)
  const int swp  = (l15 & 7) << 4;                 // P / vT row swizzle
  const floatx4 zf4 = {0.f, 0.f, 0.f, 0.f};

  // ---- hoisted global loads: weights (24 frags), biases, scale ----
  bf16x8 wvf[4][2], wff[4][4];
  #pragma unroll
  for (int kk = 0; kk < 4; ++kk) {
    #pragma unroll
    for (int ft = 0; ft < 2; ++ft)
      wvf[kk][ft] = *reinterpret_cast<const bf16x8*>(
          wqkv + (size_t)(256 + h * 32 + ft * 16 + l15) * 128 + kk * 32 + lh * 8);
    #pragma unroll
    for (int ff = 0; ff < 4; ++ff) {
      int fb = (ff < 2) ? (h * 32 + ff * 16) : (128 + h * 32 + (ff - 2) * 16);
      wff[kk][ff] = *reinterpret_cast<const bf16x8*>(
          wqkv + (size_t)(fb + l15) * 128 + kk * 32 + lh * 8);
    }
  }
  floatx4 qb0 = *reinterpret_cast<const floatx4*>(q_bias + h * 32 + lh * 4);
  floatx4 qb1 = *reinterpret_cast<const floatx4*>(q_bias + h * 32 + 16 + lh * 4);
  const float vb0 = v_bias[h * 32 + l15], vb1 = v_bias[h * 32 + 16 + l15];
  const float sc  = scale4[h];

  // ---- Phase 0: stage x tile (64x128 fp32) -> bf16 swizzled LDS ----
  {
    const float* xb = x + (size_t)b * 8192;
    int r = tid >> 2;
    #pragma unroll
    for (int cc = 0; cc < 8; ++cc) {
      int c = (tid & 3) + cc * 4;
      float4 v = reinterpret_cast<const float4*>(xb)[r * 32 + c];
      uint2 w; w.x = pkbf(v.x, v.y); w.y = pkbf(v.z, v.w);
      *reinterpret_cast<uint2*>(s_x + r * 256 + ((c * 8) ^ ((r & 7) << 4))) = w;
    }
  }
  __syncthreads();

  // ---- Phase 1 (merged): v = x@Wv^T  and  q^T,k^T = W_qk@x^T, shared xf ----
  floatx4 vacc[4][2];
  floatx4 qk[4][4];   // [ff: q0,q1,k0,k1][token tile]
  #pragma unroll
  for (int mt = 0; mt < 4; ++mt) { vacc[mt][0] = zf4; vacc[mt][1] = zf4; }
  #pragma unroll
  for (int ff = 0; ff < 4; ++ff)
    #pragma unroll
    for (int tt = 0; tt < 4; ++tt) qk[ff][tt] = zf4;

  #pragma unroll
  for (int kk = 0; kk < 4; ++kk) {
    bf16x8 xf[4];
    #pragma unroll
    for (int tt = 0; tt < 4; ++tt) {
      int row = tt * 16 + l15;
      xf[tt] = *reinterpret_cast<const bf16x8*>(
          s_x + row * 256 + (((kk * 32 + lh * 8) * 2) ^ ((row & 7) << 4)));
    }
    #pragma unroll
    for (int ft = 0; ft < 2; ++ft)
      #pragma unroll
      for (int mt = 0; mt < 4; ++mt)
        vacc[mt][ft] = __builtin_amdgcn_mfma_f32_16x16x32_bf16(xf[mt], wvf[kk][ft], vacc[mt][ft], 0, 0, 0);
    #pragma unroll
    for (int ff = 0; ff < 4; ++ff)
      #pragma unroll
      for (int tt = 0; tt < 4; ++tt)
        qk[ff][tt] = __builtin_amdgcn_mfma_f32_16x16x32_bf16(wff[kk][ff], xf[tt], qk[ff][tt], 0, 0, 0);
  }

  // v bias; vT[d][m] packed b64 writes (wave-private, no barrier needed)
  {
    char* sv = s_vT[h];
    #pragma unroll
    for (int mt = 0; mt < 4; ++mt) {
      #pragma unroll
      for (int ft = 0; ft < 2; ++ft) {
        float vb = ft ? vb1 : vb0;
        int d = ft * 16 + l15;
        uint2 w;
        w.x = pkbf(vacc[mt][ft][0] + vb, vacc[mt][ft][1] + vb);
        w.y = pkbf(vacc[mt][ft][2] + vb, vacc[mt][ft][3] + vb);
        *reinterpret_cast<uint2*>(sv + d * 128 + (((mt * 16 + lh * 4) * 2) ^ swp)) = w;
      }
    }
  }

  // q bias, lane-local cosine norms (reduce over lh groups only)
  #pragma unroll
  for (int tt = 0; tt < 4; ++tt)
    #pragma unroll
    for (int r = 0; r < 4; ++r) { qk[0][tt][r] += qb0[r]; qk[1][tt][r] += qb1[r]; }
  #pragma unroll
  for (int tt = 0; tt < 4; ++tt) {
    float sq = 0.f, sk = 0.f;
    #pragma unroll
    for (int r = 0; r < 4; ++r) {
      sq += qk[0][tt][r] * qk[0][tt][r] + qk[1][tt][r] * qk[1][tt][r];
      sk += qk[2][tt][r] * qk[2][tt][r] + qk[3][tt][r] * qk[3][tt][r];
    }
    sq += __shfl_xor(sq, 16); sq += __shfl_xor(sq, 32);
    sk += __shfl_xor(sk, 16); sk += __shfl_xor(sk, 32);
    float rq = sc  / fmaxf(sqrtf(sq), 1e-12f);
    float rk = 1.f / fmaxf(sqrtf(sk), 1e-12f);
    #pragma unroll
    for (int r = 0; r < 4; ++r) {
      qk[0][tt][r] *= rq; qk[1][tt][r] *= rq;
      qk[2][tt][r] *= rk; qk[3][tt][r] *= rk;
    }
  }

  // write q,k tiles [n][32f] (64B rows, swz swq), packed b64
  {
    char* sq = s_qk[h];
    #pragma unroll
    for (int tt = 0; tt < 4; ++tt) {
      int row = 16 * tt + l15;
      #pragma unroll
      for (int ff = 0; ff < 2; ++ff) {
        uint2 wq_, wk_;
        wq_.x = pkbf(qk[ff][tt][0],     qk[ff][tt][1]);
        wq_.y = pkbf(qk[ff][tt][2],     qk[ff][tt][3]);
        wk_.x = pkbf(qk[2 + ff][tt][0], qk[2 + ff][tt][1]);
        wk_.y = pkbf(qk[2 + ff][tt][2], qk[2 + ff][tt][3]);
        int colb = (ff * 32 + lh * 8) ^ swq;
        *reinterpret_cast<uint2*>(sq + row * 64 + colb)        = wq_;
        *reinterpret_cast<uint2*>(sq + 4096 + row * 64 + colb) = wk_;
      }
    }
  }

  // ---- Phase 2+3 fused: S^T = kn@qn^T, +bias+mask, exp, col sums, P->LDS ----
  floatx4 rs;
  {
    const char* sq = s_qk[h];
    bf16x8 qf[4], kf[4];
    #pragma unroll
    for (int tt = 0; tt < 4; ++tt) {
      int row = 16 * tt + l15;
      qf[tt] = *reinterpret_cast<const bf16x8*>(sq + row * 64 + ((lh * 16) ^ swq));
      kf[tt] = *reinterpret_cast<const bf16x8*>(sq + 4096 + row * 64 + ((lh * 16) ^ swq));
    }
    const float* bh = biasT + h * 4096;
    const float* mw = mask + (size_t)(b & 255) * 4096;
    char* sp = s_qk[h];   // P overwrites q/k (qf/kf already in regs)

    floatx4 bb[4], mm[4], bbn[4], mmn[4];
    #pragma unroll
    for (int tm = 0; tm < 4; ++tm) {
      int off = l15 * 64 + tm * 16 + lh * 4;
      bb[tm] = *reinterpret_cast<const floatx4*>(bh + off);
      mm[tm] = *reinterpret_cast<const floatx4*>(mw + off);
    }
    #pragma unroll
    for (int tn = 0; tn < 4; ++tn) {
      floatx4 sacc[4];
      #pragma unroll
      for (int tm = 0; tm < 4; ++tm)
        sacc[tm] = __builtin_amdgcn_mfma_f32_16x16x32_bf16(kf[tm], qf[tn], zf4, 0, 0, 0);
      if (tn < 3) {
        #pragma unroll
        for (int tm = 0; tm < 4; ++tm) {
          int off = ((tn + 1) * 16 + l15) * 64 + tm * 16 + lh * 4;
          bbn[tm] = *reinterpret_cast<const floatx4*>(bh + off);
          mmn[tm] = *reinterpret_cast<const floatx4*>(mw + off);
        }
      }
      float sum = 0.f;
      uint2 pw[4];
      #pragma unroll
      for (int tm = 0; tm < 4; ++tm) {
        float e0 = __expf(sacc[tm][0] + bb[tm][0] + mm[tm][0]);
        float e1 = __expf(sacc[tm][1] + bb[tm][1] + mm[tm][1]);
        float e2 = __expf(sacc[tm][2] + bb[tm][2] + mm[tm][2]);
        float e3 = __expf(sacc[tm][3] + bb[tm][3] + mm[tm][3]);
        sum += (e0 + e1) + (e2 + e3);
        pw[tm].x = pkbf(e0, e1); pw[tm].y = pkbf(e2, e3);
      }
      sum += __shfl_xor(sum, 16); sum += __shfl_xor(sum, 32);
      rs[tn] = 1.f / sum;
      int prow = 16 * tn + l15;
      #pragma unroll
      for (int tm = 0; tm < 4; ++tm)
        *reinterpret_cast<uint2*>(sp + prow * 128 + ((tm * 32 + lh * 8) ^ swp)) = pw[tm];
      #pragma unroll
      for (int tm = 0; tm < 4; ++tm) { bb[tm] = bbn[tm]; mm[tm] = mmn[tm]; }
    }
  }

  // ---- Phase 4: O^T = V^T @ P^T (both operands from wave-private LDS) ----
  floatx4 oacc[2][4];
  #pragma unroll
  for (int dt = 0; dt < 2; ++dt)
    #pragma unroll
    for (int nt = 0; nt < 4; ++nt) oacc[dt][nt] = zf4;
  {
    const char* sv = s_vT[h];
    const char* sp = s_qk[h];
    #pragma unroll
    for (int kk = 0; kk < 2; ++kk) {
      bf16x8 vf[2];
      #pragma unroll
      for (int dt = 0; dt < 2; ++dt)
        vf[dt] = *reinterpret_cast<const bf16x8*>(
            sv + (dt * 16 + l15) * 128 + ((kk * 64 + lh * 16) ^ swp));
      #pragma unroll
      for (int nt = 0; nt < 4; ++nt) {
        bf16x8 pf = *reinterpret_cast<const bf16x8*>(
            sp + (nt * 16 + l15) * 128 + ((kk * 64 + lh * 16) ^ swp));
        #pragma unroll
        for (int dt = 0; dt < 2; ++dt)
          oacc[dt][nt] = __builtin_amdgcn_mfma_f32_16x16x32_bf16(vf[dt], pf, oacc[dt][nt], 0, 0, 0);
      }
    }
  }
  __syncthreads();   // all waves done reading s_x (phase 1) before O overwrites it

  // O (scaled by 1/rowsum) -> s_x as [n][c] bf16, b64-packed writes
  #pragma unroll
  for (int dt = 0; dt < 2; ++dt) {
    #pragma unroll
    for (int nt = 0; nt < 4; ++nt) {
      int n = nt * 16 + l15;
      uint2 w;
      w.x = pkbf(oacc[dt][nt][0] * rs[nt], oacc[dt][nt][1] * rs[nt]);
      w.y = pkbf(oacc[dt][nt][2] * rs[nt], oacc[dt][nt][3] * rs[nt]);
      *reinterpret_cast<uint2*>(
          s_x + n * 256 + (((h * 32 + dt * 16 + lh * 4) * 2) ^ ((n & 7) << 4))) = w;
    }
  }
  __syncthreads();

  // ---- Phase 5: proj GEMM + bias, fp32 store ----
  floatx4 pacc[4][2];
  #pragma unroll
  for (int mt = 0; mt < 4; ++mt) { pacc[mt][0] = zf4; pacc[mt][1] = zf4; }
  #pragma unroll
  for (int kk = 0; kk < 4; ++kk) {
    bf16x8 of[4];
    #pragma unroll
    for (int mt = 0; mt < 4; ++mt) {
      int row = mt * 16 + l15;
      of[mt] = *reinterpret_cast<const bf16x8*>(
          s_x + row * 256 + (((kk * 32 + lh * 8) * 2) ^ ((row & 7) << 4)));
    }
    #pragma unroll
    for (int ft = 0; ft < 2; ++ft) {
      bf16x8 wp = *reinterpret_cast<const bf16x8*>(
          wproj + (size_t)(h * 32 + ft * 16 + l15) * 128 + kk * 32 + lh * 8);
      #pragma unroll
      for (int mt = 0; mt < 4; ++mt)
        pacc[mt][ft] = __builtin_amdgcn_mfma_f32_16x16x32_bf16(of[mt], wp, pacc[mt][ft], 0, 0, 0);
    }
  }
  {
    float pb0 = proj_b[h * 32 + l15], pb1 = proj_b[h * 32 + 16 + l15];
    float* ob = out + (size_t)b * 8192;
    #pragma unroll
    for (int mt = 0; mt < 4; ++mt)
      #pragma unroll
      for (int r = 0; r < 4; ++r) {
        int n = mt * 16 + lh * 4 + r;
        ob[n * 128 + h * 32 + l15]      = pacc[mt][0][r] + pb0;
        ob[n * 128 + h * 32 + 16 + l15] = pacc[mt][1][r] + pb1;
      }
  }
}

extern "C" void kernel_launch(void* const* d_in, const int* in_sizes, int n_in,
                              void* d_out, int out_size, void* d_ws, size_t ws_size,
                              hipStream_t stream)
{
  const float* x    = (const float*)d_in[0];
  const float* mask = (const float*)d_in[1];
  const float* qkvw = (const float*)d_in[2];
  const float* qb   = (const float*)d_in[3];
  const float* vb   = (const float*)d_in[4];
  const float* ls   = (const float*)d_in[5];
  const float* w1   = (const float*)d_in[6];
  const float* b1   = (const float*)d_in[7];
  const float* w2   = (const float*)d_in[8];
  const float* pw   = (const float*)d_in[9];
  const float* pb   = (const float*)d_in[10];
  float* out = (float*)d_out;
  char* ws = (char*)d_ws;

  unsigned short* wsQ = (unsigned short*)ws;   // qkv bf16 [0,49152) + proj bf16 [49152,65536)
  float* wsBias  = (float*)(ws + WS_BIAS);
  float* wsScale = (float*)(ws + WS_SCALE);
  float* wsTbl   = (float*)(ws + WS_TBL);

  hipLaunchKernelGGL(k_prep_weights, dim3(64), dim3(256), 0, stream, qkvw, pw, ls, wsQ, wsScale);
  hipLaunchKernelGGL(k_cpb_table, dim3(225), dim3(256), 0, stream, w1, b1, w2, wsTbl);
  hipLaunchKernelGGL(k_cpb_bias, dim3(64), dim3(256), 0, stream, wsTbl, wsBias);
  hipLaunchKernelGGL(k_wmsa, dim3(8192), dim3(256), 0, stream, x, mask,
                     wsQ, wsQ + 49152, qb, vb, wsBias, wsScale, pb, out);
}